// Round 5
// baseline (388.079 us; speedup 1.0000x reference)
//
#include <hip/hip_runtime.h>

// GNN_17575006175684: 3-layer GCN + mean-pool + linear head + log_softmax.
// R5: CSR via exact two-level MSD counting sort -> col writes are sequential,
// zero global cursor atomics, no write-amplified random scatter:
//   hist1     : per-chunk LDS histogram of dst>>9 (256 groups of 512 nodes)
//   scan_cnt  : scan of 256 x nChunks count matrix -> exact offsets + groupBeg
//   scatter1  : (dst,src) int2 into group-major buckets (LDS-atomic local
//               ranks; within-group order irrelevant)
//   group_csr : one block per group: LDS 512-bin hist of dst&511 + LDS scan
//               -> row_ptr/dinv coalesced; col scattered within the block's
//               OWN 32KB window (one CU -> one L2; lines written once).
//               Within-bucket order arbitrary == same-dst edges interchangeable.
// Layers: gather-before-transform (A(XW)=(AX)W), prescale Xs=dinv*X, fused
// matmul epilogue (dinv, bias, relu, next prescale). Pool+head atomic-free.

#define BLK 256
#define CH 4096             // edges per chunk in pass 1
#define EPT (CH / BLK)      // 16
#define NB 256              // pass-1 buckets = dst>>9 (512 nodes each)
#define GSH 9
#define GSZ 512

// ---------------- pass 1: coarse bucket by dst>>9 ----------------

__global__ void hist1_kernel(const int* __restrict__ dst, int* __restrict__ cnt,
                             int E, int nChunks) {
    __shared__ int h[NB];
    int t = threadIdx.x, b = blockIdx.x;
    h[t] = 0;
    __syncthreads();
    int base = b * CH;
#pragma unroll
    for (int j = 0; j < EPT; ++j) {
        int e = base + j * BLK + t;
        if (e < E) atomicAdd(&h[dst[e] >> GSH], 1);
    }
    __syncthreads();
    cnt[(size_t)t * nChunks + b] = h[t];   // bucket-major
}

// single block: in-place exclusive scan of cnt[M]; emit groupBeg[0..NB]
__global__ void scan_cnt_kernel(int* __restrict__ cnt, int* __restrict__ groupBeg,
                                int M, int nChunks, int E) {
    __shared__ int part[256];
    int t = threadIdx.x;
    int per = (M + 255) / 256;
    int lo = t * per, hi = lo + per < M ? lo + per : M;
    int sum = 0;
    for (int i = lo; i < hi; ++i) sum += cnt[i];
    part[t] = sum;
    __syncthreads();
    for (int off = 1; off < 256; off <<= 1) {
        int x = (t >= off) ? part[t - off] : 0;
        __syncthreads();
        if (t >= off) part[t] += x;
        __syncthreads();
    }
    int run = part[t] - sum;   // exclusive
    for (int i = lo; i < hi; ++i) { int v = cnt[i]; cnt[i] = run; run += v; }
    __syncthreads();
    groupBeg[t] = cnt[(size_t)t * nChunks];
    if (t == 0) groupBeg[NB] = E;
}

__global__ void scatter1_kernel(const int* __restrict__ src, const int* __restrict__ dst,
                                const int* __restrict__ cnt, int2* __restrict__ e2,
                                int E, int nChunks) {
    __shared__ int offs[NB];
    int t = threadIdx.x, b = blockIdx.x;
    offs[t] = cnt[(size_t)t * nChunks + b];
    __syncthreads();
    int base = b * CH;
#pragma unroll
    for (int j = 0; j < EPT; ++j) {
        int e = base + j * BLK + t;
        if (e < E) {
            int d = dst[e];
            int p = atomicAdd(&offs[d >> GSH], 1);
            e2[p] = make_int2(d, src[e]);
        }
    }
}

// ---------------- pass 2: one block per 512-node group ----------------

__global__ void group_csr_kernel(const int2* __restrict__ e2, const int* __restrict__ groupBeg,
                                 int* __restrict__ col, int* __restrict__ row_ptr,
                                 float* __restrict__ dinv, int N, int E) {
    __shared__ int hist[GSZ];
    __shared__ int scn[GSZ];
    __shared__ int part[256];
    int g = blockIdx.x, t = threadIdx.x;
    hist[t] = 0; hist[t + 256] = 0;
    __syncthreads();
    int lo = groupBeg[g], hi = groupBeg[g + 1];
    for (int e = lo + t; e < hi; e += BLK)
        atomicAdd(&hist[e2[e].x & (GSZ - 1)], 1);
    __syncthreads();
    // exclusive scan of hist[512] with 256 threads
    int a0 = hist[2 * t], a1 = hist[2 * t + 1];
    int s2 = a0 + a1;
    part[t] = s2;
    __syncthreads();
    for (int off = 1; off < 256; off <<= 1) {
        int x = (t >= off) ? part[t - off] : 0;
        __syncthreads();
        if (t >= off) part[t] += x;
        __syncthreads();
    }
    int excl = part[t] - s2;
    scn[2 * t] = excl;
    scn[2 * t + 1] = excl + a0;
    __syncthreads();
    // row_ptr + dinv (coalesced, this block's own nodes)
#pragma unroll
    for (int i = t; i < GSZ; i += BLK) {
        int d = (g << GSH) + i;
        if (d < N) {
            row_ptr[d] = lo + scn[i];
            dinv[d] = rsqrtf((float)hist[i] + 1.0f);   // +1 self-loop
        }
    }
    if (g == 0 && t == 0) row_ptr[N] = E;
    __syncthreads();
    // reuse hist as cursors (relative)
    hist[t] = scn[t]; hist[t + 256] = scn[t + 256];
    __syncthreads();
    for (int e = lo + t; e < hi; e += BLK) {
        int2 v = e2[e];
        int p = atomicAdd(&hist[v.x & (GSZ - 1)], 1);
        col[lo + p] = v.y;   // within this block's 32KB window only
    }
}

// ---------------- layers ----------------

__global__ void prescale1_kernel(const float* __restrict__ x, const float* __restrict__ dinv,
                                 float* __restrict__ xs, int N) {
    int idx = blockIdx.x * blockDim.x + threadIdx.x;
    if (idx >= N * 5) return;
    int n = idx / 5;
    xs[idx] = x[idx] * dinv[n];
}

template <int F>
__global__ void gather_kernel(const int* __restrict__ row_ptr, const int* __restrict__ col,
                              const float* __restrict__ xs, float* __restrict__ g, int N) {
    int idx = blockIdx.x * blockDim.x + threadIdx.x;
    if (idx >= N * F) return;
    int n = idx / F, f = idx % F;
    int beg = row_ptr[n], end = row_ptr[n + 1];
    float acc = xs[idx];
    int e = beg;
    for (; e + 3 < end; e += 4) {
        int s0 = col[e], s1 = col[e + 1], s2 = col[e + 2], s3 = col[e + 3];
        float a = xs[s0 * F + f], b = xs[s1 * F + f];
        float c = xs[s2 * F + f], d = xs[s3 * F + f];
        acc += a + b + c + d;
    }
    for (; e < end; ++e) acc += xs[col[e] * F + f];
    g[idx] = acc;
}

template <int F>
__global__ void gather4_kernel(const int* __restrict__ row_ptr, const int* __restrict__ col,
                               const float4* __restrict__ xs, float4* __restrict__ g, int N) {
    constexpr int FQ = F / 4;
    int idx = blockIdx.x * blockDim.x + threadIdx.x;
    if (idx >= N * FQ) return;
    int n = idx / FQ, q = idx % FQ;
    int beg = row_ptr[n], end = row_ptr[n + 1];
    float4 acc = xs[n * FQ + q];
    int e = beg;
    for (; e + 3 < end; e += 4) {
        int s0 = col[e], s1 = col[e + 1], s2 = col[e + 2], s3 = col[e + 3];
        float4 a = xs[s0 * FQ + q];
        float4 b = xs[s1 * FQ + q];
        float4 c = xs[s2 * FQ + q];
        float4 d = xs[s3 * FQ + q];
        acc.x += a.x + b.x + c.x + d.x;
        acc.y += a.y + b.y + c.y + d.y;
        acc.z += a.z + b.z + c.z + d.z;
        acc.w += a.w + b.w + c.w + d.w;
    }
    for (; e < end; ++e) {
        float4 a = xs[col[e] * FQ + q];
        acc.x += a.x; acc.y += a.y; acc.z += a.z; acc.w += a.w;
    }
    g[n * FQ + q] = acc;
}

template <int FIN, int FOUT, bool PRESCALE_OUT>
__global__ void matmul_kernel(const float* __restrict__ g, const float* __restrict__ W,
                              const float* __restrict__ b, const float* __restrict__ dinv,
                              float* __restrict__ out, int N) {
    int idx = blockIdx.x * blockDim.x + threadIdx.x;
    if (idx >= N * FOUT) return;
    int n = idx / FOUT, f = idx % FOUT;
    float di = dinv[n];
    float acc = 0.f;
    const float* row = g + n * FIN;
#pragma unroll
    for (int k = 0; k < FIN; ++k)
        acc = fmaf(row[k], W[k * FOUT + f], acc);
    float v = fmaxf(di * acc + b[f], 0.f);
    out[idx] = PRESCALE_OUT ? v * di : v;
}

// ---------------- pool + head (atomic-free) ----------------

__global__ void bounds_kernel(const int* __restrict__ batch, int* __restrict__ start,
                              int N, int G) {
    int g = blockIdx.x * blockDim.x + threadIdx.x;
    if (g > G) return;
    if (g == G) { start[G] = N; return; }
    int lo = 0, hi = N;
    while (lo < hi) {
        int mid = (lo + hi) >> 1;
        if (batch[mid] < g) lo = mid + 1; else hi = mid;
    }
    start[g] = lo;
}

__global__ void pool_head_kernel(const float* __restrict__ h, const int* __restrict__ start,
                                 const float* __restrict__ Wfc, const float* __restrict__ bfc,
                                 float* __restrict__ out) {
    __shared__ float part[4][64];
    int g = blockIdx.x;
    int t = threadIdx.x;          // 256
    int f = t & 63, w = t >> 6;
    int s = start[g], e = start[g + 1];
    float acc = 0.f;
    for (int n = s + w; n < e; n += 4)
        acc += h[(size_t)n * 64 + f];
    part[w][f] = acc;
    __syncthreads();
    if (w == 0) {
        float p = part[0][f] + part[1][f] + part[2][f] + part[3][f];
        p /= fmaxf((float)(e - s), 1.0f);
        float l0 = p * Wfc[f * 2 + 0];
        float l1 = p * Wfc[f * 2 + 1];
#pragma unroll
        for (int off = 32; off; off >>= 1) {
            l0 += __shfl_down(l0, off);
            l1 += __shfl_down(l1, off);
        }
        if (f == 0) {
            l0 += bfc[0]; l1 += bfc[1];
            float m   = fmaxf(l0, l1);
            float lse = m + logf(expf(l0 - m) + expf(l1 - m));
            out[g * 2 + 0] = l0 - lse;
            out[g * 2 + 1] = l1 - lse;
        }
    }
}

// ---------------- driver ----------------

extern "C" void kernel_launch(void* const* d_in, const int* in_sizes, int n_in,
                              void* d_out, int out_size, void* d_ws, size_t ws_size,
                              hipStream_t stream) {
    const float* x     = (const float*)d_in[0];
    const int*   src   = (const int*)d_in[1];
    const int*   dst   = (const int*)d_in[2];
    const int*   batch = (const int*)d_in[3];
    const float* W1    = (const float*)d_in[4];
    const float* b1    = (const float*)d_in[5];
    const float* W2    = (const float*)d_in[6];
    const float* b2    = (const float*)d_in[7];
    const float* W3    = (const float*)d_in[8];
    const float* b3    = (const float*)d_in[9];
    const float* Wfc   = (const float*)d_in[10];
    const float* bfc   = (const float*)d_in[11];
    float* out = (float*)d_out;

    const int N = in_sizes[0] / 5;   // 100000
    const int E = in_sizes[1];       // 1600000
    const int G = out_size / 2;      // 1024

    const int nChunks = (E + CH - 1) / CH;           // 391
    const int M       = NB * nChunks;                // ~100K
    const int Mpad    = (M + 3) & ~3;
    const int nGroups = (N + GSZ - 1) / GSZ;         // 196

    // workspace layout (4B units; region sizes multiples of 4 -> 16B aligned)
    int* row_ptr  = (int*)d_ws;                   // N+4 (uses N+1)
    int* col      = row_ptr + N + 4;              // E
    int* cnt      = col + E;                      // Mpad
    int* groupBeg = cnt + Mpad;                   // 260 (uses NB+1)
    int* start    = groupBeg + 260;               // G+8 (uses G+1)
    float* dinv   = (float*)(start + G + 8);      // N
    float* A      = dinv + N;                     // N*64
    float* B      = A + (size_t)N * 64;           // N*64
    int2* e2      = (int2*)A;                     // E int2 (aliases A; dead before layers)
    // total ~ 60 MB

    auto blocks = [](long n) { return (int)((n + BLK - 1) / BLK); };

    // ---- CSR build: exact counting sort, no memsets, no global atomics ----
    hist1_kernel<<<nChunks, 256, 0, stream>>>(dst, cnt, E, nChunks);
    scan_cnt_kernel<<<1, 256, 0, stream>>>(cnt, groupBeg, M, nChunks, E);
    scatter1_kernel<<<nChunks, 256, 0, stream>>>(src, dst, cnt, e2, E, nChunks);
    group_csr_kernel<<<nGroups, 256, 0, stream>>>(e2, groupBeg, col, row_ptr, dinv, N, E);

    // ---- pool boundaries ----
    bounds_kernel<<<blocks(G + 1), BLK, 0, stream>>>(batch, start, N, G);

    // ---- layer 1: x[N,5] -> Xs2 in B[N,16] ----
    prescale1_kernel<<<blocks((long)N * 5), BLK, 0, stream>>>(x, dinv, B, N);              // B = Xs1 [N,5]
    gather_kernel<5><<<blocks((long)N * 5), BLK, 0, stream>>>(row_ptr, col, B, A, N);      // A = g1  [N,5]
    matmul_kernel<5, 16, true><<<blocks((long)N * 16), BLK, 0, stream>>>(A, W1, b1, dinv, B, N);  // B = Xs2 [N,16]

    // ---- layer 2: B[N,16] -> Xs3 in B[N,32] ----
    gather4_kernel<16><<<blocks((long)N * 4), BLK, 0, stream>>>(row_ptr, col,
        (const float4*)B, (float4*)A, N);                                                  // A = g2 [N,16]
    matmul_kernel<16, 32, true><<<blocks((long)N * 32), BLK, 0, stream>>>(A, W2, b2, dinv, B, N); // B = Xs3 [N,32]

    // ---- layer 3: B[N,32] -> out3 in B[N,64] (via A) ----
    gather4_kernel<32><<<blocks((long)N * 8), BLK, 0, stream>>>(row_ptr, col,
        (const float4*)B, (float4*)A, N);                                                  // A = g3 [N,32]
    matmul_kernel<32, 64, false><<<blocks((long)N * 64), BLK, 0, stream>>>(A, W3, b3, dinv, B, N); // B = out3 [N,64]

    // ---- mean pool + head (no atomics) ----
    pool_head_kernel<<<G, 256, 0, stream>>>(B, start, Wfc, bfc, out);
}

// Round 6
// 231.566 us; speedup vs baseline: 1.6759x; 1.6759x over previous
//
#include <hip/hip_runtime.h>

// GNN_17575006175684: 3-layer GCN + mean-pool + linear head + log_softmax.
// R6 = R5 (two-level MSD counting-sort CSR, sequential col writes, no global
// cursor atomics) with the scan bottleneck fixed: the 100K-entry offset scan
// is separable into 256 independent per-bucket scans (seg_scan, 256 blocks)
// + a 256-entry bucket-total scan (bucket_scan, 1 block); scatter1 adds the
// bucket base in-kernel. R5's single-block serial scan was 166us (latency on
// one CU); this is <10us.

#define BLK 256
#define CH 4096             // edges per chunk in pass 1
#define EPT (CH / BLK)      // 16
#define NB 256              // pass-1 buckets = dst>>9 (512 nodes each)
#define GSH 9
#define GSZ 512

// ---------------- pass 1: coarse bucket by dst>>9 ----------------

__global__ void hist1_kernel(const int* __restrict__ dst, int* __restrict__ cnt,
                             int E, int nChunks) {
    __shared__ int h[NB];
    int t = threadIdx.x, b = blockIdx.x;
    h[t] = 0;
    __syncthreads();
    int base = b * CH;
#pragma unroll
    for (int j = 0; j < EPT; ++j) {
        int e = base + j * BLK + t;
        if (e < E) atomicAdd(&h[dst[e] >> GSH], 1);
    }
    __syncthreads();
    cnt[(size_t)t * nChunks + b] = h[t];   // bucket-major
}

// 256 blocks, one per bucket: exclusive scan of cnt[b*nChunks .. +nChunks),
// bucket total -> bucketTot[b]
__global__ void seg_scan_kernel(int* __restrict__ cnt, int* __restrict__ bucketTot,
                                int nChunks) {
    __shared__ int part[256];
    int b = blockIdx.x, t = threadIdx.x;
    size_t base = (size_t)b * nChunks;
    int per = (nChunks + 255) / 256;
    int lo = t * per, hi = lo + per < nChunks ? lo + per : nChunks;
    int sum = 0;
    for (int i = lo; i < hi; ++i) sum += cnt[base + i];
    part[t] = sum;
    __syncthreads();
    for (int off = 1; off < 256; off <<= 1) {
        int x = (t >= off) ? part[t - off] : 0;
        __syncthreads();
        if (t >= off) part[t] += x;
        __syncthreads();
    }
    int run = part[t] - sum;   // exclusive
    for (int i = lo; i < hi; ++i) { int v = cnt[base + i]; cnt[base + i] = run; run += v; }
    if (t == 255) bucketTot[b] = part[255];
}

// 1 block: exclusive scan of bucketTot[256] -> groupBeg[0..NB]
__global__ void bucket_scan_kernel(const int* __restrict__ bucketTot,
                                   int* __restrict__ groupBeg, int E) {
    __shared__ int part[256];
    int t = threadIdx.x;
    int v = bucketTot[t];
    part[t] = v;
    __syncthreads();
    for (int off = 1; off < 256; off <<= 1) {
        int x = (t >= off) ? part[t - off] : 0;
        __syncthreads();
        if (t >= off) part[t] += x;
        __syncthreads();
    }
    groupBeg[t] = part[t] - v;   // exclusive
    if (t == 0) groupBeg[NB] = E;
}

__global__ void scatter1_kernel(const int* __restrict__ src, const int* __restrict__ dst,
                                const int* __restrict__ cnt, const int* __restrict__ groupBeg,
                                int2* __restrict__ e2, int E, int nChunks) {
    __shared__ int offs[NB];
    int t = threadIdx.x, b = blockIdx.x;
    offs[t] = cnt[(size_t)t * nChunks + b] + groupBeg[t];
    __syncthreads();
    int base = b * CH;
#pragma unroll
    for (int j = 0; j < EPT; ++j) {
        int e = base + j * BLK + t;
        if (e < E) {
            int d = dst[e];
            int p = atomicAdd(&offs[d >> GSH], 1);
            e2[p] = make_int2(d, src[e]);
        }
    }
}

// ---------------- pass 2: one block per 512-node group ----------------

__global__ void group_csr_kernel(const int2* __restrict__ e2, const int* __restrict__ groupBeg,
                                 int* __restrict__ col, int* __restrict__ row_ptr,
                                 float* __restrict__ dinv, int N, int E) {
    __shared__ int hist[GSZ];
    __shared__ int scn[GSZ];
    __shared__ int part[256];
    int g = blockIdx.x, t = threadIdx.x;
    hist[t] = 0; hist[t + 256] = 0;
    __syncthreads();
    int lo = groupBeg[g], hi = groupBeg[g + 1];
    for (int e = lo + t; e < hi; e += BLK)
        atomicAdd(&hist[e2[e].x & (GSZ - 1)], 1);
    __syncthreads();
    // exclusive scan of hist[512] with 256 threads
    int a0 = hist[2 * t], a1 = hist[2 * t + 1];
    int s2 = a0 + a1;
    part[t] = s2;
    __syncthreads();
    for (int off = 1; off < 256; off <<= 1) {
        int x = (t >= off) ? part[t - off] : 0;
        __syncthreads();
        if (t >= off) part[t] += x;
        __syncthreads();
    }
    int excl = part[t] - s2;
    scn[2 * t] = excl;
    scn[2 * t + 1] = excl + a0;
    __syncthreads();
    // row_ptr + dinv (coalesced, this block's own nodes)
#pragma unroll
    for (int i = t; i < GSZ; i += BLK) {
        int d = (g << GSH) + i;
        if (d < N) {
            row_ptr[d] = lo + scn[i];
            dinv[d] = rsqrtf((float)hist[i] + 1.0f);   // +1 self-loop
        }
    }
    if (g == 0 && t == 0) row_ptr[N] = E;
    __syncthreads();
    // reuse hist as cursors (relative)
    hist[t] = scn[t]; hist[t + 256] = scn[t + 256];
    __syncthreads();
    for (int e = lo + t; e < hi; e += BLK) {
        int2 v = e2[e];
        int p = atomicAdd(&hist[v.x & (GSZ - 1)], 1);
        col[lo + p] = v.y;   // within this block's 32KB window only
    }
}

// ---------------- layers ----------------

__global__ void prescale1_kernel(const float* __restrict__ x, const float* __restrict__ dinv,
                                 float* __restrict__ xs, int N) {
    int idx = blockIdx.x * blockDim.x + threadIdx.x;
    if (idx >= N * 5) return;
    int n = idx / 5;
    xs[idx] = x[idx] * dinv[n];
}

template <int F>
__global__ void gather_kernel(const int* __restrict__ row_ptr, const int* __restrict__ col,
                              const float* __restrict__ xs, float* __restrict__ g, int N) {
    int idx = blockIdx.x * blockDim.x + threadIdx.x;
    if (idx >= N * F) return;
    int n = idx / F, f = idx % F;
    int beg = row_ptr[n], end = row_ptr[n + 1];
    float acc = xs[idx];
    int e = beg;
    for (; e + 3 < end; e += 4) {
        int s0 = col[e], s1 = col[e + 1], s2 = col[e + 2], s3 = col[e + 3];
        float a = xs[s0 * F + f], b = xs[s1 * F + f];
        float c = xs[s2 * F + f], d = xs[s3 * F + f];
        acc += a + b + c + d;
    }
    for (; e < end; ++e) acc += xs[col[e] * F + f];
    g[idx] = acc;
}

template <int F>
__global__ void gather4_kernel(const int* __restrict__ row_ptr, const int* __restrict__ col,
                               const float4* __restrict__ xs, float4* __restrict__ g, int N) {
    constexpr int FQ = F / 4;
    int idx = blockIdx.x * blockDim.x + threadIdx.x;
    if (idx >= N * FQ) return;
    int n = idx / FQ, q = idx % FQ;
    int beg = row_ptr[n], end = row_ptr[n + 1];
    float4 acc = xs[n * FQ + q];
    int e = beg;
    for (; e + 3 < end; e += 4) {
        int s0 = col[e], s1 = col[e + 1], s2 = col[e + 2], s3 = col[e + 3];
        float4 a = xs[s0 * FQ + q];
        float4 b = xs[s1 * FQ + q];
        float4 c = xs[s2 * FQ + q];
        float4 d = xs[s3 * FQ + q];
        acc.x += a.x + b.x + c.x + d.x;
        acc.y += a.y + b.y + c.y + d.y;
        acc.z += a.z + b.z + c.z + d.z;
        acc.w += a.w + b.w + c.w + d.w;
    }
    for (; e < end; ++e) {
        float4 a = xs[col[e] * FQ + q];
        acc.x += a.x; acc.y += a.y; acc.z += a.z; acc.w += a.w;
    }
    g[n * FQ + q] = acc;
}

template <int FIN, int FOUT, bool PRESCALE_OUT>
__global__ void matmul_kernel(const float* __restrict__ g, const float* __restrict__ W,
                              const float* __restrict__ b, const float* __restrict__ dinv,
                              float* __restrict__ out, int N) {
    int idx = blockIdx.x * blockDim.x + threadIdx.x;
    if (idx >= N * FOUT) return;
    int n = idx / FOUT, f = idx % FOUT;
    float di = dinv[n];
    float acc = 0.f;
    const float* row = g + n * FIN;
#pragma unroll
    for (int k = 0; k < FIN; ++k)
        acc = fmaf(row[k], W[k * FOUT + f], acc);
    float v = fmaxf(di * acc + b[f], 0.f);
    out[idx] = PRESCALE_OUT ? v * di : v;
}

// ---------------- pool + head (atomic-free) ----------------

__global__ void bounds_kernel(const int* __restrict__ batch, int* __restrict__ start,
                              int N, int G) {
    int g = blockIdx.x * blockDim.x + threadIdx.x;
    if (g > G) return;
    if (g == G) { start[G] = N; return; }
    int lo = 0, hi = N;
    while (lo < hi) {
        int mid = (lo + hi) >> 1;
        if (batch[mid] < g) lo = mid + 1; else hi = mid;
    }
    start[g] = lo;
}

__global__ void pool_head_kernel(const float* __restrict__ h, const int* __restrict__ start,
                                 const float* __restrict__ Wfc, const float* __restrict__ bfc,
                                 float* __restrict__ out) {
    __shared__ float part[4][64];
    int g = blockIdx.x;
    int t = threadIdx.x;          // 256
    int f = t & 63, w = t >> 6;
    int s = start[g], e = start[g + 1];
    float acc = 0.f;
    for (int n = s + w; n < e; n += 4)
        acc += h[(size_t)n * 64 + f];
    part[w][f] = acc;
    __syncthreads();
    if (w == 0) {
        float p = part[0][f] + part[1][f] + part[2][f] + part[3][f];
        p /= fmaxf((float)(e - s), 1.0f);
        float l0 = p * Wfc[f * 2 + 0];
        float l1 = p * Wfc[f * 2 + 1];
#pragma unroll
        for (int off = 32; off; off >>= 1) {
            l0 += __shfl_down(l0, off);
            l1 += __shfl_down(l1, off);
        }
        if (f == 0) {
            l0 += bfc[0]; l1 += bfc[1];
            float m   = fmaxf(l0, l1);
            float lse = m + logf(expf(l0 - m) + expf(l1 - m));
            out[g * 2 + 0] = l0 - lse;
            out[g * 2 + 1] = l1 - lse;
        }
    }
}

// ---------------- driver ----------------

extern "C" void kernel_launch(void* const* d_in, const int* in_sizes, int n_in,
                              void* d_out, int out_size, void* d_ws, size_t ws_size,
                              hipStream_t stream) {
    const float* x     = (const float*)d_in[0];
    const int*   src   = (const int*)d_in[1];
    const int*   dst   = (const int*)d_in[2];
    const int*   batch = (const int*)d_in[3];
    const float* W1    = (const float*)d_in[4];
    const float* b1    = (const float*)d_in[5];
    const float* W2    = (const float*)d_in[6];
    const float* b2    = (const float*)d_in[7];
    const float* W3    = (const float*)d_in[8];
    const float* b3    = (const float*)d_in[9];
    const float* Wfc   = (const float*)d_in[10];
    const float* bfc   = (const float*)d_in[11];
    float* out = (float*)d_out;

    const int N = in_sizes[0] / 5;   // 100000
    const int E = in_sizes[1];       // 1600000
    const int G = out_size / 2;      // 1024

    const int nChunks = (E + CH - 1) / CH;           // 391
    const int M       = NB * nChunks;                // ~100K
    const int Mpad    = (M + 3) & ~3;
    const int nGroups = (N + GSZ - 1) / GSZ;         // 196

    // workspace layout (4B units; region sizes multiples of 4 -> 16B aligned)
    int* row_ptr  = (int*)d_ws;                   // N+4 (uses N+1)
    int* col      = row_ptr + N + 4;              // E
    int* cnt      = col + E;                      // Mpad
    int* groupBeg = cnt + Mpad;                   // 260 (uses NB+1)
    int* bucketTot= groupBeg + 260;               // 256
    int* start    = bucketTot + 256;              // G+8 (uses G+1)
    float* dinv   = (float*)(start + G + 8);      // N
    float* A      = dinv + N;                     // N*64
    float* B      = A + (size_t)N * 64;           // N*64
    int2* e2      = (int2*)A;                     // E int2 (aliases A; dead before layers)
    // total ~ 60 MB

    auto blocks = [](long n) { return (int)((n + BLK - 1) / BLK); };

    // ---- CSR build: exact counting sort; parallel separable scan ----
    hist1_kernel<<<nChunks, 256, 0, stream>>>(dst, cnt, E, nChunks);
    seg_scan_kernel<<<NB, 256, 0, stream>>>(cnt, bucketTot, nChunks);
    bucket_scan_kernel<<<1, 256, 0, stream>>>(bucketTot, groupBeg, E);
    scatter1_kernel<<<nChunks, 256, 0, stream>>>(src, dst, cnt, groupBeg, e2, E, nChunks);
    group_csr_kernel<<<nGroups, 256, 0, stream>>>(e2, groupBeg, col, row_ptr, dinv, N, E);

    // ---- pool boundaries ----
    bounds_kernel<<<blocks(G + 1), BLK, 0, stream>>>(batch, start, N, G);

    // ---- layer 1: x[N,5] -> Xs2 in B[N,16] ----
    prescale1_kernel<<<blocks((long)N * 5), BLK, 0, stream>>>(x, dinv, B, N);              // B = Xs1 [N,5]
    gather_kernel<5><<<blocks((long)N * 5), BLK, 0, stream>>>(row_ptr, col, B, A, N);      // A = g1  [N,5]
    matmul_kernel<5, 16, true><<<blocks((long)N * 16), BLK, 0, stream>>>(A, W1, b1, dinv, B, N);  // B = Xs2 [N,16]

    // ---- layer 2: B[N,16] -> Xs3 in B[N,32] ----
    gather4_kernel<16><<<blocks((long)N * 4), BLK, 0, stream>>>(row_ptr, col,
        (const float4*)B, (float4*)A, N);                                                  // A = g2 [N,16]
    matmul_kernel<16, 32, true><<<blocks((long)N * 32), BLK, 0, stream>>>(A, W2, b2, dinv, B, N); // B = Xs3 [N,32]

    // ---- layer 3: B[N,32] -> out3 in B[N,64] (via A) ----
    gather4_kernel<32><<<blocks((long)N * 8), BLK, 0, stream>>>(row_ptr, col,
        (const float4*)B, (float4*)A, N);                                                  // A = g3 [N,32]
    matmul_kernel<32, 64, false><<<blocks((long)N * 64), BLK, 0, stream>>>(A, W3, b3, dinv, B, N); // B = out3 [N,64]

    // ---- mean pool + head (no atomics) ----
    pool_head_kernel<<<G, 256, 0, stream>>>(B, start, Wfc, bfc, out);
}

// Round 7
// 209.700 us; speedup vs baseline: 1.8506x; 1.1043x over previous
//
#include <hip/hip_runtime.h>

// GNN_17575006175684: 3-layer GCN + mean-pool + linear head + log_softmax.
// R7 = R6 (counting-sort CSR) + vectorized layers:
//   matmul4    : 4 outputs/thread, float4 row/W/store, 4 indep FMA chains
//                (R6 matmul3 was 52us at 8% HBM / 15% VALU -- narrow-instr bound)
//   gather_lds : block stages its node-range's col[] slab into LDS once
//                (coalesced), killing the FQ-fold redundant global index loads;
//                guarded global fallback if slab exceeds LDS cap (never at
//                these stats, but correctness does not depend on that)
//   layer-1 input padded to stride 8 -> float4 gather path for F=5.
// Pool+head atomic-free; prescale Xs=dinv*X; fused matmul epilogue.

#define BLK 256
#define CH 4096             // edges per chunk in pass 1
#define EPT (CH / BLK)      // 16
#define NB 256              // pass-1 buckets = dst>>9 (512 nodes each)
#define GSH 9
#define GSZ 512

// ---------------- pass 1: coarse bucket by dst>>9 ----------------

__global__ void hist1_kernel(const int* __restrict__ dst, int* __restrict__ cnt,
                             int E, int nChunks) {
    __shared__ int h[NB];
    int t = threadIdx.x, b = blockIdx.x;
    h[t] = 0;
    __syncthreads();
    int base = b * CH;
#pragma unroll
    for (int j = 0; j < EPT; ++j) {
        int e = base + j * BLK + t;
        if (e < E) atomicAdd(&h[dst[e] >> GSH], 1);
    }
    __syncthreads();
    cnt[(size_t)t * nChunks + b] = h[t];   // bucket-major
}

__global__ void seg_scan_kernel(int* __restrict__ cnt, int* __restrict__ bucketTot,
                                int nChunks) {
    __shared__ int part[256];
    int b = blockIdx.x, t = threadIdx.x;
    size_t base = (size_t)b * nChunks;
    int per = (nChunks + 255) / 256;
    int lo = t * per, hi = lo + per < nChunks ? lo + per : nChunks;
    int sum = 0;
    for (int i = lo; i < hi; ++i) sum += cnt[base + i];
    part[t] = sum;
    __syncthreads();
    for (int off = 1; off < 256; off <<= 1) {
        int x = (t >= off) ? part[t - off] : 0;
        __syncthreads();
        if (t >= off) part[t] += x;
        __syncthreads();
    }
    int run = part[t] - sum;   // exclusive
    for (int i = lo; i < hi; ++i) { int v = cnt[base + i]; cnt[base + i] = run; run += v; }
    if (t == 255) bucketTot[b] = part[255];
}

__global__ void bucket_scan_kernel(const int* __restrict__ bucketTot,
                                   int* __restrict__ groupBeg, int E) {
    __shared__ int part[256];
    int t = threadIdx.x;
    int v = bucketTot[t];
    part[t] = v;
    __syncthreads();
    for (int off = 1; off < 256; off <<= 1) {
        int x = (t >= off) ? part[t - off] : 0;
        __syncthreads();
        if (t >= off) part[t] += x;
        __syncthreads();
    }
    groupBeg[t] = part[t] - v;   // exclusive
    if (t == 0) groupBeg[NB] = E;
}

__global__ void scatter1_kernel(const int* __restrict__ src, const int* __restrict__ dst,
                                const int* __restrict__ cnt, const int* __restrict__ groupBeg,
                                int2* __restrict__ e2, int E, int nChunks) {
    __shared__ int offs[NB];
    int t = threadIdx.x, b = blockIdx.x;
    offs[t] = cnt[(size_t)t * nChunks + b] + groupBeg[t];
    __syncthreads();
    int base = b * CH;
#pragma unroll
    for (int j = 0; j < EPT; ++j) {
        int e = base + j * BLK + t;
        if (e < E) {
            int d = dst[e];
            int p = atomicAdd(&offs[d >> GSH], 1);
            e2[p] = make_int2(d, src[e]);
        }
    }
}

// ---------------- pass 2: one block per 512-node group ----------------

__global__ void group_csr_kernel(const int2* __restrict__ e2, const int* __restrict__ groupBeg,
                                 int* __restrict__ col, int* __restrict__ row_ptr,
                                 float* __restrict__ dinv, int N, int E) {
    __shared__ int hist[GSZ];
    __shared__ int scn[GSZ];
    __shared__ int part[256];
    int g = blockIdx.x, t = threadIdx.x;
    hist[t] = 0; hist[t + 256] = 0;
    __syncthreads();
    int lo = groupBeg[g], hi = groupBeg[g + 1];
    for (int e = lo + t; e < hi; e += BLK)
        atomicAdd(&hist[e2[e].x & (GSZ - 1)], 1);
    __syncthreads();
    int a0 = hist[2 * t], a1 = hist[2 * t + 1];
    int s2 = a0 + a1;
    part[t] = s2;
    __syncthreads();
    for (int off = 1; off < 256; off <<= 1) {
        int x = (t >= off) ? part[t - off] : 0;
        __syncthreads();
        if (t >= off) part[t] += x;
        __syncthreads();
    }
    int excl = part[t] - s2;
    scn[2 * t] = excl;
    scn[2 * t + 1] = excl + a0;
    __syncthreads();
#pragma unroll
    for (int i = t; i < GSZ; i += BLK) {
        int d = (g << GSH) + i;
        if (d < N) {
            row_ptr[d] = lo + scn[i];
            dinv[d] = rsqrtf((float)hist[i] + 1.0f);   // +1 self-loop
        }
    }
    if (g == 0 && t == 0) row_ptr[N] = E;
    __syncthreads();
    hist[t] = scn[t]; hist[t + 256] = scn[t + 256];
    __syncthreads();
    for (int e = lo + t; e < hi; e += BLK) {
        int2 v = e2[e];
        int p = atomicAdd(&hist[v.x & (GSZ - 1)], 1);
        col[lo + p] = v.y;   // within this block's 32KB window only
    }
}

// ---------------- layers ----------------

// x[N,5] -> xs[N,8] padded, prescaled by dinv
__global__ void prescale1_kernel(const float* __restrict__ x, const float* __restrict__ dinv,
                                 float* __restrict__ xs, int N) {
    int idx = blockIdx.x * blockDim.x + threadIdx.x;
    if (idx >= N * 8) return;
    int n = idx >> 3, k = idx & 7;
    xs[idx] = (k < 5) ? x[n * 5 + k] * dinv[n] : 0.f;
}

// block stages its node-range's col slab into LDS, then float4 gathers.
// CAP: mean slab = NPB*16; CAP >= mean + 30 sigma; global fallback keeps
// correctness for any degree distribution.
template <int F, int CAP>
__global__ void gather_lds_kernel(const int* __restrict__ row_ptr, const int* __restrict__ col,
                                  const float4* __restrict__ xs, float4* __restrict__ g, int N) {
    constexpr int FQ = F / 4;
    constexpr int NPB = 256 / FQ;
    __shared__ int lcol[CAP];
    __shared__ int lrp[NPB + 1];
    int t = threadIdx.x;
    int n0 = blockIdx.x * NPB;
    if (t <= NPB) lrp[t] = row_ptr[min(n0 + t, N)];
    __syncthreads();
    int base = lrp[0];
    int total = lrp[NPB] - base;
    int stage = total < CAP ? total : CAP;
    for (int i = t; i < stage; i += 256) lcol[i] = col[base + i];
    __syncthreads();
    int ln = t / FQ, q = t % FQ;
    int n = n0 + ln;
    if (n >= N) return;
    int beg = lrp[ln] - base, end = lrp[ln + 1] - base;
    float4 acc = xs[(size_t)n * FQ + q];
    int e = beg;
    for (; e < end && e < stage; ++e) {
        int s = lcol[e];
        float4 a = xs[(size_t)s * FQ + q];
        acc.x += a.x; acc.y += a.y; acc.z += a.z; acc.w += a.w;
    }
    for (; e < end; ++e) {   // cold overflow fallback
        int s = col[base + e];
        float4 a = xs[(size_t)s * FQ + q];
        acc.x += a.x; acc.y += a.y; acc.z += a.z; acc.w += a.w;
    }
    g[(size_t)n * FQ + q] = acc;
}

// 4 outputs/thread: out[n, 4q..4q+3] = relu(dinv*(row @ W) + b) [* dinv]
template <int FIN, int ISTRIDE, int FOUT, bool PRESCALE_OUT>
__global__ void matmul4_kernel(const float* __restrict__ g, const float* __restrict__ W,
                               const float* __restrict__ b, const float* __restrict__ dinv,
                               float* __restrict__ out, int N) {
    constexpr int QO = FOUT / 4;
    int idx = blockIdx.x * blockDim.x + threadIdx.x;
    if (idx >= N * QO) return;
    int n = idx / QO, q = idx % QO;
    float di = dinv[n];
    const float* row = g + (size_t)n * ISTRIDE;
    float r[FIN];
    if constexpr (FIN % 4 == 0) {
#pragma unroll
        for (int k4 = 0; k4 < FIN / 4; ++k4)
            *(float4*)(r + 4 * k4) = *(const float4*)(row + 4 * k4);
    } else {
#pragma unroll
        for (int k = 0; k < FIN; ++k) r[k] = row[k];
    }
    float4 acc = make_float4(0.f, 0.f, 0.f, 0.f);
#pragma unroll
    for (int k = 0; k < FIN; ++k) {
        float4 wk = *(const float4*)(W + (size_t)k * FOUT + 4 * q);
        acc.x = fmaf(r[k], wk.x, acc.x);
        acc.y = fmaf(r[k], wk.y, acc.y);
        acc.z = fmaf(r[k], wk.z, acc.z);
        acc.w = fmaf(r[k], wk.w, acc.w);
    }
    float4 bq = *(const float4*)(b + 4 * q);
    float4 v;
    v.x = fmaxf(di * acc.x + bq.x, 0.f);
    v.y = fmaxf(di * acc.y + bq.y, 0.f);
    v.z = fmaxf(di * acc.z + bq.z, 0.f);
    v.w = fmaxf(di * acc.w + bq.w, 0.f);
    if (PRESCALE_OUT) { v.x *= di; v.y *= di; v.z *= di; v.w *= di; }
    *(float4*)(out + (size_t)n * FOUT + 4 * q) = v;
}

// ---------------- pool + head (atomic-free) ----------------

__global__ void bounds_kernel(const int* __restrict__ batch, int* __restrict__ start,
                              int N, int G) {
    int g = blockIdx.x * blockDim.x + threadIdx.x;
    if (g > G) return;
    if (g == G) { start[G] = N; return; }
    int lo = 0, hi = N;
    while (lo < hi) {
        int mid = (lo + hi) >> 1;
        if (batch[mid] < g) lo = mid + 1; else hi = mid;
    }
    start[g] = lo;
}

__global__ void pool_head_kernel(const float* __restrict__ h, const int* __restrict__ start,
                                 const float* __restrict__ Wfc, const float* __restrict__ bfc,
                                 float* __restrict__ out) {
    __shared__ float part[4][64];
    int g = blockIdx.x;
    int t = threadIdx.x;          // 256
    int f = t & 63, w = t >> 6;
    int s = start[g], e = start[g + 1];
    float acc = 0.f;
    for (int n = s + w; n < e; n += 4)
        acc += h[(size_t)n * 64 + f];
    part[w][f] = acc;
    __syncthreads();
    if (w == 0) {
        float p = part[0][f] + part[1][f] + part[2][f] + part[3][f];
        p /= fmaxf((float)(e - s), 1.0f);
        float l0 = p * Wfc[f * 2 + 0];
        float l1 = p * Wfc[f * 2 + 1];
#pragma unroll
        for (int off = 32; off; off >>= 1) {
            l0 += __shfl_down(l0, off);
            l1 += __shfl_down(l1, off);
        }
        if (f == 0) {
            l0 += bfc[0]; l1 += bfc[1];
            float m   = fmaxf(l0, l1);
            float lse = m + logf(expf(l0 - m) + expf(l1 - m));
            out[g * 2 + 0] = l0 - lse;
            out[g * 2 + 1] = l1 - lse;
        }
    }
}

// ---------------- driver ----------------

extern "C" void kernel_launch(void* const* d_in, const int* in_sizes, int n_in,
                              void* d_out, int out_size, void* d_ws, size_t ws_size,
                              hipStream_t stream) {
    const float* x     = (const float*)d_in[0];
    const int*   src   = (const int*)d_in[1];
    const int*   dst   = (const int*)d_in[2];
    const int*   batch = (const int*)d_in[3];
    const float* W1    = (const float*)d_in[4];
    const float* b1    = (const float*)d_in[5];
    const float* W2    = (const float*)d_in[6];
    const float* b2    = (const float*)d_in[7];
    const float* W3    = (const float*)d_in[8];
    const float* b3    = (const float*)d_in[9];
    const float* Wfc   = (const float*)d_in[10];
    const float* bfc   = (const float*)d_in[11];
    float* out = (float*)d_out;

    const int N = in_sizes[0] / 5;   // 100000
    const int E = in_sizes[1];       // 1600000
    const int G = out_size / 2;      // 1024

    const int nChunks = (E + CH - 1) / CH;           // 391
    const int M       = NB * nChunks;                // ~100K
    const int Mpad    = (M + 3) & ~3;
    const int nGroups = (N + GSZ - 1) / GSZ;         // 196

    // workspace layout (4B units; region sizes multiples of 4 -> 16B aligned)
    int* row_ptr  = (int*)d_ws;                   // N+4 (uses N+1)
    int* col      = row_ptr + N + 4;              // E
    int* cnt      = col + E;                      // Mpad
    int* groupBeg = cnt + Mpad;                   // 260 (uses NB+1)
    int* bucketTot= groupBeg + 260;               // 256
    int* start    = bucketTot + 256;              // G+8 (uses G+1)
    float* dinv   = (float*)(start + G + 8);      // N
    float* A      = dinv + N;                     // N*64
    float* B      = A + (size_t)N * 64;           // N*64
    int2* e2      = (int2*)A;                     // E int2 (aliases A; dead before layers)
    // total ~ 60 MB

    auto blocks = [](long n) { return (int)((n + BLK - 1) / BLK); };

    // ---- CSR build: exact counting sort; parallel separable scan ----
    hist1_kernel<<<nChunks, 256, 0, stream>>>(dst, cnt, E, nChunks);
    seg_scan_kernel<<<NB, 256, 0, stream>>>(cnt, bucketTot, nChunks);
    bucket_scan_kernel<<<1, 256, 0, stream>>>(bucketTot, groupBeg, E);
    scatter1_kernel<<<nChunks, 256, 0, stream>>>(src, dst, cnt, groupBeg, e2, E, nChunks);
    group_csr_kernel<<<nGroups, 256, 0, stream>>>(e2, groupBeg, col, row_ptr, dinv, N, E);

    // ---- pool boundaries ----
    bounds_kernel<<<blocks(G + 1), BLK, 0, stream>>>(batch, start, N, G);

    // ---- layer 1: x[N,5] -> Xs2 in B[N,16]  (padded stride-8 path) ----
    prescale1_kernel<<<blocks((long)N * 8), BLK, 0, stream>>>(x, dinv, B, N);              // B = Xs1 [N,8]
    {   // A = g1 [N,8]
        constexpr int NPB = 256 / 2;   // F=8 -> FQ=2
        gather_lds_kernel<8, 4096><<<(N + NPB - 1) / NPB, 256, 0, stream>>>(
            row_ptr, col, (const float4*)B, (float4*)A, N);
    }
    matmul4_kernel<5, 8, 16, true><<<blocks((long)N * 4), BLK, 0, stream>>>(A, W1, b1, dinv, B, N);  // B = Xs2 [N,16]

    // ---- layer 2: B[N,16] -> Xs3 in B[N,32] ----
    {   // A = g2 [N,16]
        constexpr int NPB = 256 / 4;   // F=16 -> FQ=4
        gather_lds_kernel<16, 2048><<<(N + NPB - 1) / NPB, 256, 0, stream>>>(
            row_ptr, col, (const float4*)B, (float4*)A, N);
    }
    matmul4_kernel<16, 16, 32, true><<<blocks((long)N * 8), BLK, 0, stream>>>(A, W2, b2, dinv, B, N); // B = Xs3 [N,32]

    // ---- layer 3: B[N,32] -> out3 in B[N,64] (via A) ----
    {   // A = g3 [N,32]
        constexpr int NPB = 256 / 8;   // F=32 -> FQ=8
        gather_lds_kernel<32, 2048><<<(N + NPB - 1) / NPB, 256, 0, stream>>>(
            row_ptr, col, (const float4*)B, (float4*)A, N);
    }
    matmul4_kernel<32, 32, 64, false><<<blocks((long)N * 16), BLK, 0, stream>>>(A, W3, b3, dinv, B, N); // B = out3 [N,64]

    // ---- mean pool + head (no atomics) ----
    pool_head_kernel<<<G, 256, 0, stream>>>(B, start, Wfc, bfc, out);
}

// Round 8
// 172.845 us; speedup vs baseline: 2.2452x; 1.2132x over previous
//
#include <hip/hip_runtime.h>

// GNN_17575006175684: 3-layer GCN + mean-pool + linear head + log_softmax.
// R8 = R7 (counting-sort CSR + LDS-staged gather + matmul4) with the gather
// feature tables stored in BF16 (accumulation/matmul/pool all stay fp32):
// F=32 row = 64B = one cache line (was 128B) -> halves the random-gather
// L2/L3 traffic that dominated R7 (gather FETCH 147MB, 49us). Storage-only
// rounding (2^-9 rel) averages out in mean-pool; expected absmax ~1e-3 vs
// 1.4e-2 threshold.

#define BLK 256
#define CH 4096             // edges per chunk in pass 1
#define EPT (CH / BLK)      // 16
#define NB 256              // pass-1 buckets = dst>>9 (512 nodes each)
#define GSH 9
#define GSZ 512

// ---------------- bf16 helpers (storage only) ----------------

__device__ inline float bfu_lo(unsigned int w) { return __uint_as_float(w << 16); }
__device__ inline float bfu_hi(unsigned int w) { return __uint_as_float(w & 0xffff0000u); }
__device__ inline unsigned int f2bf(float f) {   // RNE, returns in low 16 bits
    unsigned int w = __float_as_uint(f);
    return (w + 0x7fffu + ((w >> 16) & 1u)) >> 16;
}
__device__ inline unsigned int pack2(float a, float b) {
    return f2bf(a) | (f2bf(b) << 16);
}

// ---------------- pass 1: coarse bucket by dst>>9 ----------------

__global__ void hist1_kernel(const int* __restrict__ dst, int* __restrict__ cnt,
                             int E, int nChunks) {
    __shared__ int h[NB];
    int t = threadIdx.x, b = blockIdx.x;
    h[t] = 0;
    __syncthreads();
    int base = b * CH;
#pragma unroll
    for (int j = 0; j < EPT; ++j) {
        int e = base + j * BLK + t;
        if (e < E) atomicAdd(&h[dst[e] >> GSH], 1);
    }
    __syncthreads();
    cnt[(size_t)t * nChunks + b] = h[t];   // bucket-major
}

__global__ void seg_scan_kernel(int* __restrict__ cnt, int* __restrict__ bucketTot,
                                int nChunks) {
    __shared__ int part[256];
    int b = blockIdx.x, t = threadIdx.x;
    size_t base = (size_t)b * nChunks;
    int per = (nChunks + 255) / 256;
    int lo = t * per, hi = lo + per < nChunks ? lo + per : nChunks;
    int sum = 0;
    for (int i = lo; i < hi; ++i) sum += cnt[base + i];
    part[t] = sum;
    __syncthreads();
    for (int off = 1; off < 256; off <<= 1) {
        int x = (t >= off) ? part[t - off] : 0;
        __syncthreads();
        if (t >= off) part[t] += x;
        __syncthreads();
    }
    int run = part[t] - sum;   // exclusive
    for (int i = lo; i < hi; ++i) { int v = cnt[base + i]; cnt[base + i] = run; run += v; }
    if (t == 255) bucketTot[b] = part[255];
}

__global__ void bucket_scan_kernel(const int* __restrict__ bucketTot,
                                   int* __restrict__ groupBeg, int E) {
    __shared__ int part[256];
    int t = threadIdx.x;
    int v = bucketTot[t];
    part[t] = v;
    __syncthreads();
    for (int off = 1; off < 256; off <<= 1) {
        int x = (t >= off) ? part[t - off] : 0;
        __syncthreads();
        if (t >= off) part[t] += x;
        __syncthreads();
    }
    groupBeg[t] = part[t] - v;   // exclusive
    if (t == 0) groupBeg[NB] = E;
}

__global__ void scatter1_kernel(const int* __restrict__ src, const int* __restrict__ dst,
                                const int* __restrict__ cnt, const int* __restrict__ groupBeg,
                                int2* __restrict__ e2, int E, int nChunks) {
    __shared__ int offs[NB];
    int t = threadIdx.x, b = blockIdx.x;
    offs[t] = cnt[(size_t)t * nChunks + b] + groupBeg[t];
    __syncthreads();
    int base = b * CH;
#pragma unroll
    for (int j = 0; j < EPT; ++j) {
        int e = base + j * BLK + t;
        if (e < E) {
            int d = dst[e];
            int p = atomicAdd(&offs[d >> GSH], 1);
            e2[p] = make_int2(d, src[e]);
        }
    }
}

// ---------------- pass 2: one block per 512-node group ----------------

__global__ void group_csr_kernel(const int2* __restrict__ e2, const int* __restrict__ groupBeg,
                                 int* __restrict__ col, int* __restrict__ row_ptr,
                                 float* __restrict__ dinv, int N, int E) {
    __shared__ int hist[GSZ];
    __shared__ int scn[GSZ];
    __shared__ int part[256];
    int g = blockIdx.x, t = threadIdx.x;
    hist[t] = 0; hist[t + 256] = 0;
    __syncthreads();
    int lo = groupBeg[g], hi = groupBeg[g + 1];
    for (int e = lo + t; e < hi; e += BLK)
        atomicAdd(&hist[e2[e].x & (GSZ - 1)], 1);
    __syncthreads();
    int a0 = hist[2 * t], a1 = hist[2 * t + 1];
    int s2 = a0 + a1;
    part[t] = s2;
    __syncthreads();
    for (int off = 1; off < 256; off <<= 1) {
        int x = (t >= off) ? part[t - off] : 0;
        __syncthreads();
        if (t >= off) part[t] += x;
        __syncthreads();
    }
    int excl = part[t] - s2;
    scn[2 * t] = excl;
    scn[2 * t + 1] = excl + a0;
    __syncthreads();
#pragma unroll
    for (int i = t; i < GSZ; i += BLK) {
        int d = (g << GSH) + i;
        if (d < N) {
            row_ptr[d] = lo + scn[i];
            dinv[d] = rsqrtf((float)hist[i] + 1.0f);   // +1 self-loop
        }
    }
    if (g == 0 && t == 0) row_ptr[N] = E;
    __syncthreads();
    hist[t] = scn[t]; hist[t + 256] = scn[t + 256];
    __syncthreads();
    for (int e = lo + t; e < hi; e += BLK) {
        int2 v = e2[e];
        int p = atomicAdd(&hist[v.x & (GSZ - 1)], 1);
        col[lo + p] = v.y;   // within this block's 32KB window only
    }
}

// ---------------- layers ----------------

// x[N,5] fp32 -> xb[N,8] bf16 padded, prescaled by dinv (one uint4 row/thread)
__global__ void prescale1_kernel(const float* __restrict__ x, const float* __restrict__ dinv,
                                 uint4* __restrict__ xb, int N) {
    int n = blockIdx.x * blockDim.x + threadIdx.x;
    if (n >= N) return;
    float di = dinv[n];
    const float* r = x + (size_t)n * 5;
    float v0 = r[0] * di, v1 = r[1] * di, v2 = r[2] * di, v3 = r[3] * di, v4 = r[4] * di;
    uint4 u;
    u.x = pack2(v0, v1);
    u.y = pack2(v2, v3);
    u.z = pack2(v4, 0.f);
    u.w = 0u;
    xb[n] = u;
}

// bf16 gather: TPN = F/8 threads per node, each owns one 16B chunk (8 bf16).
// Block stages its node-range's col[] slab into LDS once (coalesced);
// guarded global fallback keeps correctness for any degree distribution.
template <int F, int CAP>
__global__ void gather_bf_kernel(const int* __restrict__ row_ptr, const int* __restrict__ col,
                                 const uint4* __restrict__ xb, float4* __restrict__ g, int N) {
    constexpr int TPN = F / 8;
    constexpr int NPB = 256 / TPN;
    constexpr int RQ  = F / 8;   // uint4 per bf16 row
    __shared__ int lcol[CAP];
    __shared__ int lrp[NPB + 1];
    int t = threadIdx.x;
    int n0 = blockIdx.x * NPB;
    for (int i = t; i <= NPB; i += 256) lrp[i] = row_ptr[min(n0 + i, N)];
    __syncthreads();
    int base = lrp[0];
    int total = lrp[NPB] - base;
    int stage = total < CAP ? total : CAP;
    for (int i = t; i < stage; i += 256) lcol[i] = col[base + i];
    __syncthreads();
    int ln = t / TPN, q = t % TPN;
    int n = n0 + ln;
    if (n >= N) return;
    int beg = lrp[ln] - base, end = lrp[ln + 1] - base;
    float acc[8];
    {
        uint4 u = xb[(size_t)n * RQ + q];   // self term
        acc[0] = bfu_lo(u.x); acc[1] = bfu_hi(u.x);
        acc[2] = bfu_lo(u.y); acc[3] = bfu_hi(u.y);
        acc[4] = bfu_lo(u.z); acc[5] = bfu_hi(u.z);
        acc[6] = bfu_lo(u.w); acc[7] = bfu_hi(u.w);
    }
    int e = beg;
    int stop = end < stage ? end : stage;
    for (; e + 3 < stop; e += 4) {   // 4 outstanding loads
        int s0 = lcol[e], s1 = lcol[e + 1], s2 = lcol[e + 2], s3 = lcol[e + 3];
        uint4 u0 = xb[(size_t)s0 * RQ + q];
        uint4 u1 = xb[(size_t)s1 * RQ + q];
        uint4 u2 = xb[(size_t)s2 * RQ + q];
        uint4 u3 = xb[(size_t)s3 * RQ + q];
        acc[0] += bfu_lo(u0.x) + bfu_lo(u1.x) + bfu_lo(u2.x) + bfu_lo(u3.x);
        acc[1] += bfu_hi(u0.x) + bfu_hi(u1.x) + bfu_hi(u2.x) + bfu_hi(u3.x);
        acc[2] += bfu_lo(u0.y) + bfu_lo(u1.y) + bfu_lo(u2.y) + bfu_lo(u3.y);
        acc[3] += bfu_hi(u0.y) + bfu_hi(u1.y) + bfu_hi(u2.y) + bfu_hi(u3.y);
        acc[4] += bfu_lo(u0.z) + bfu_lo(u1.z) + bfu_lo(u2.z) + bfu_lo(u3.z);
        acc[5] += bfu_hi(u0.z) + bfu_hi(u1.z) + bfu_hi(u2.z) + bfu_hi(u3.z);
        acc[6] += bfu_lo(u0.w) + bfu_lo(u1.w) + bfu_lo(u2.w) + bfu_lo(u3.w);
        acc[7] += bfu_hi(u0.w) + bfu_hi(u1.w) + bfu_hi(u2.w) + bfu_hi(u3.w);
    }
    for (; e < end; ++e) {
        int s = (e < stage) ? lcol[e] : col[base + e];
        uint4 u = xb[(size_t)s * RQ + q];
        acc[0] += bfu_lo(u.x); acc[1] += bfu_hi(u.x);
        acc[2] += bfu_lo(u.y); acc[3] += bfu_hi(u.y);
        acc[4] += bfu_lo(u.z); acc[5] += bfu_hi(u.z);
        acc[6] += bfu_lo(u.w); acc[7] += bfu_hi(u.w);
    }
    size_t gq = ((size_t)n * F + q * 8) >> 2;
    g[gq]     = make_float4(acc[0], acc[1], acc[2], acc[3]);
    g[gq + 1] = make_float4(acc[4], acc[5], acc[6], acc[7]);
}

// 4 outputs/thread; fp32 input row (stride ISTRIDE), fused epilogue
// relu(dinv*acc + b) [* dinv]; output bf16 (uint2 row chunk) or fp32 (float4).
template <int FIN, int ISTRIDE, int FOUT, bool PRESCALE_OUT, bool BF16_OUT>
__global__ void matmul4_kernel(const float* __restrict__ g, const float* __restrict__ W,
                               const float* __restrict__ b, const float* __restrict__ dinv,
                               void* __restrict__ outv, int N) {
    constexpr int QO = FOUT / 4;
    int idx = blockIdx.x * blockDim.x + threadIdx.x;
    if (idx >= N * QO) return;
    int n = idx / QO, q = idx % QO;
    float di = dinv[n];
    const float* row = g + (size_t)n * ISTRIDE;
    float r[FIN];
    if constexpr (FIN % 4 == 0) {
#pragma unroll
        for (int k4 = 0; k4 < FIN / 4; ++k4)
            *(float4*)(r + 4 * k4) = *(const float4*)(row + 4 * k4);
    } else {
#pragma unroll
        for (int k = 0; k < FIN; ++k) r[k] = row[k];
    }
    float4 acc = make_float4(0.f, 0.f, 0.f, 0.f);
#pragma unroll
    for (int k = 0; k < FIN; ++k) {
        float4 wk = *(const float4*)(W + (size_t)k * FOUT + 4 * q);
        acc.x = fmaf(r[k], wk.x, acc.x);
        acc.y = fmaf(r[k], wk.y, acc.y);
        acc.z = fmaf(r[k], wk.z, acc.z);
        acc.w = fmaf(r[k], wk.w, acc.w);
    }
    float4 bq = *(const float4*)(b + 4 * q);
    float4 v;
    v.x = fmaxf(di * acc.x + bq.x, 0.f);
    v.y = fmaxf(di * acc.y + bq.y, 0.f);
    v.z = fmaxf(di * acc.z + bq.z, 0.f);
    v.w = fmaxf(di * acc.w + bq.w, 0.f);
    if (PRESCALE_OUT) { v.x *= di; v.y *= di; v.z *= di; v.w *= di; }
    if constexpr (BF16_OUT) {
        uint2 u;
        u.x = pack2(v.x, v.y);
        u.y = pack2(v.z, v.w);
        ((uint2*)outv)[(size_t)n * QO + q] = u;   // bf16 row chunk (8B)
    } else {
        ((float4*)outv)[(size_t)n * QO + q] = v;
    }
}

// ---------------- pool + head (atomic-free) ----------------

__global__ void bounds_kernel(const int* __restrict__ batch, int* __restrict__ start,
                              int N, int G) {
    int g = blockIdx.x * blockDim.x + threadIdx.x;
    if (g > G) return;
    if (g == G) { start[G] = N; return; }
    int lo = 0, hi = N;
    while (lo < hi) {
        int mid = (lo + hi) >> 1;
        if (batch[mid] < g) lo = mid + 1; else hi = mid;
    }
    start[g] = lo;
}

__global__ void pool_head_kernel(const float* __restrict__ h, const int* __restrict__ start,
                                 const float* __restrict__ Wfc, const float* __restrict__ bfc,
                                 float* __restrict__ out) {
    __shared__ float part[4][64];
    int g = blockIdx.x;
    int t = threadIdx.x;          // 256
    int f = t & 63, w = t >> 6;
    int s = start[g], e = start[g + 1];
    float acc = 0.f;
    for (int n = s + w; n < e; n += 4)
        acc += h[(size_t)n * 64 + f];
    part[w][f] = acc;
    __syncthreads();
    if (w == 0) {
        float p = part[0][f] + part[1][f] + part[2][f] + part[3][f];
        p /= fmaxf((float)(e - s), 1.0f);
        float l0 = p * Wfc[f * 2 + 0];
        float l1 = p * Wfc[f * 2 + 1];
#pragma unroll
        for (int off = 32; off; off >>= 1) {
            l0 += __shfl_down(l0, off);
            l1 += __shfl_down(l1, off);
        }
        if (f == 0) {
            l0 += bfc[0]; l1 += bfc[1];
            float m   = fmaxf(l0, l1);
            float lse = m + logf(expf(l0 - m) + expf(l1 - m));
            out[g * 2 + 0] = l0 - lse;
            out[g * 2 + 1] = l1 - lse;
        }
    }
}

// ---------------- driver ----------------

extern "C" void kernel_launch(void* const* d_in, const int* in_sizes, int n_in,
                              void* d_out, int out_size, void* d_ws, size_t ws_size,
                              hipStream_t stream) {
    const float* x     = (const float*)d_in[0];
    const int*   src   = (const int*)d_in[1];
    const int*   dst   = (const int*)d_in[2];
    const int*   batch = (const int*)d_in[3];
    const float* W1    = (const float*)d_in[4];
    const float* b1    = (const float*)d_in[5];
    const float* W2    = (const float*)d_in[6];
    const float* b2    = (const float*)d_in[7];
    const float* W3    = (const float*)d_in[8];
    const float* b3    = (const float*)d_in[9];
    const float* Wfc   = (const float*)d_in[10];
    const float* bfc   = (const float*)d_in[11];
    float* out = (float*)d_out;

    const int N = in_sizes[0] / 5;   // 100000
    const int E = in_sizes[1];       // 1600000
    const int G = out_size / 2;      // 1024

    const int nChunks = (E + CH - 1) / CH;           // 391
    const int M       = NB * nChunks;                // ~100K
    const int Mpad    = (M + 3) & ~3;
    const int nGroups = (N + GSZ - 1) / GSZ;         // 196

    // workspace layout (4B units; region sizes multiples of 4 -> 16B aligned)
    int* row_ptr  = (int*)d_ws;                   // N+4 (uses N+1)
    int* col      = row_ptr + N + 4;              // E
    int* cnt      = col + E;                      // Mpad
    int* groupBeg = cnt + Mpad;                   // 260 (uses NB+1)
    int* bucketTot= groupBeg + 260;               // 256
    int* start    = bucketTot + 256;              // G+8 (uses G+1)
    float* dinv   = (float*)(start + G + 8);      // N
    int*   Xb     = (int*)(dinv + N);             // N*16 ints (bf16 [N,<=32])
    float* Gf     = (float*)(Xb + (size_t)N * 16);// N*32 fp32 (gather out)
    float* H3     = Gf + (size_t)N * 32;          // N*64 fp32 (final feats)
    int2*  e2     = (int2*)H3;                    // E int2 (aliases H3; dead before layer3)
    // total ~ 53 MB

    auto blocks = [](long n) { return (int)((n + BLK - 1) / BLK); };

    // ---- CSR build: exact counting sort; parallel separable scan ----
    hist1_kernel<<<nChunks, 256, 0, stream>>>(dst, cnt, E, nChunks);
    seg_scan_kernel<<<NB, 256, 0, stream>>>(cnt, bucketTot, nChunks);
    bucket_scan_kernel<<<1, 256, 0, stream>>>(bucketTot, groupBeg, E);
    scatter1_kernel<<<nChunks, 256, 0, stream>>>(src, dst, cnt, groupBeg, e2, E, nChunks);
    group_csr_kernel<<<nGroups, 256, 0, stream>>>(e2, groupBeg, col, row_ptr, dinv, N, E);

    // ---- pool boundaries ----
    bounds_kernel<<<blocks(G + 1), BLK, 0, stream>>>(batch, start, N, G);

    // ---- layer 1: x[N,5] -> Xs2(bf16) in Xb[N,16] ----
    prescale1_kernel<<<blocks(N), BLK, 0, stream>>>(x, dinv, (uint4*)Xb, N);   // Xb = Xs1 bf16 [N,8]
    gather_bf_kernel<8, 8192><<<(N + 255) / 256, 256, 0, stream>>>(
        row_ptr, col, (const uint4*)Xb, (float4*)Gf, N);                       // Gf = g1 fp32 [N,8]
    matmul4_kernel<5, 8, 16, true, true><<<blocks((long)N * 4), BLK, 0, stream>>>(
        Gf, W1, b1, dinv, Xb, N);                                              // Xb = Xs2 bf16 [N,16]

    // ---- layer 2 ----
    gather_bf_kernel<16, 4096><<<(N + 127) / 128, 256, 0, stream>>>(
        row_ptr, col, (const uint4*)Xb, (float4*)Gf, N);                       // Gf = g2 fp32 [N,16]
    matmul4_kernel<16, 16, 32, true, true><<<blocks((long)N * 8), BLK, 0, stream>>>(
        Gf, W2, b2, dinv, Xb, N);                                              // Xb = Xs3 bf16 [N,32]

    // ---- layer 3 ----
    gather_bf_kernel<32, 2048><<<(N + 63) / 64, 256, 0, stream>>>(
        row_ptr, col, (const uint4*)Xb, (float4*)Gf, N);                       // Gf = g3 fp32 [N,32]
    matmul4_kernel<32, 32, 64, false, false><<<blocks((long)N * 16), BLK, 0, stream>>>(
        Gf, W3, b3, dinv, H3, N);                                              // H3 = out3 fp32 [N,64]

    // ---- mean pool + head (no atomics) ----
    pool_head_kernel<<<G, 256, 0, stream>>>(H3, start, Wfc, bfc, out);
}

// Round 9
// 130.691 us; speedup vs baseline: 2.9694x; 1.3226x over previous
//
#include <hip/hip_runtime.h>

// GNN_17575006175684: 3-layer GCN + mean-pool + linear head + log_softmax.
// R9 = R8 with:
//  - packed 4B edge bucket: pe = (dst&511)<<17 | src  (src < 2^17) -> halves
//    scatter1 write + group_csr read traffic
//  - prescale fused into group_csr (it computes dinv and owns the node range)
//  - gather+matmul fused per layer: gathered rows -> LDS (+1 pad), W/b in LDS,
//    matmul reads LDS; kills the Gf fp32 round-trip (~45MB) and 3 launches
//  - H3 stored bf16 -> matmul3 write + pool read halved
// All accumulation fp32; bf16 is storage-only (R8 absmax was 0.0 -> margin).
// Buffer ping-pong: Xa(Xs1)->Xb(Xs2)->Xa(Xs3)->H3b, no read/write overlap.

#define BLK 256
#define CH 4096             // edges per chunk in pass 1
#define EPT (CH / BLK)      // 16
#define NB 256              // pass-1 buckets = dst>>9 (512 nodes each)
#define GSH 9
#define GSZ 512

// ---------------- bf16 helpers (storage only) ----------------

__device__ inline float bfu_lo(unsigned int w) { return __uint_as_float(w << 16); }
__device__ inline float bfu_hi(unsigned int w) { return __uint_as_float(w & 0xffff0000u); }
__device__ inline unsigned int f2bf(float f) {   // RNE
    unsigned int w = __float_as_uint(f);
    return (w + 0x7fffu + ((w >> 16) & 1u)) >> 16;
}
__device__ inline unsigned int pack2(float a, float b) {
    return f2bf(a) | (f2bf(b) << 16);
}

// ---------------- pass 1: coarse bucket by dst>>9 ----------------

__global__ void hist1_kernel(const int* __restrict__ dst, int* __restrict__ cnt,
                             int E, int nChunks) {
    __shared__ int h[NB];
    int t = threadIdx.x, b = blockIdx.x;
    h[t] = 0;
    __syncthreads();
    int base = b * CH;
#pragma unroll
    for (int j = 0; j < EPT; ++j) {
        int e = base + j * BLK + t;
        if (e < E) atomicAdd(&h[dst[e] >> GSH], 1);
    }
    __syncthreads();
    cnt[(size_t)t * nChunks + b] = h[t];   // bucket-major
}

__global__ void seg_scan_kernel(int* __restrict__ cnt, int* __restrict__ bucketTot,
                                int nChunks) {
    __shared__ int part[256];
    int b = blockIdx.x, t = threadIdx.x;
    size_t base = (size_t)b * nChunks;
    int per = (nChunks + 255) / 256;
    int lo = t * per, hi = lo + per < nChunks ? lo + per : nChunks;
    int sum = 0;
    for (int i = lo; i < hi; ++i) sum += cnt[base + i];
    part[t] = sum;
    __syncthreads();
    for (int off = 1; off < 256; off <<= 1) {
        int x = (t >= off) ? part[t - off] : 0;
        __syncthreads();
        if (t >= off) part[t] += x;
        __syncthreads();
    }
    int run = part[t] - sum;   // exclusive
    for (int i = lo; i < hi; ++i) { int v = cnt[base + i]; cnt[base + i] = run; run += v; }
    if (t == 255) bucketTot[b] = part[255];
}

__global__ void bucket_scan_kernel(const int* __restrict__ bucketTot,
                                   int* __restrict__ groupBeg, int E) {
    __shared__ int part[256];
    int t = threadIdx.x;
    int v = bucketTot[t];
    part[t] = v;
    __syncthreads();
    for (int off = 1; off < 256; off <<= 1) {
        int x = (t >= off) ? part[t - off] : 0;
        __syncthreads();
        if (t >= off) part[t] += x;
        __syncthreads();
    }
    groupBeg[t] = part[t] - v;   // exclusive
    if (t == 0) groupBeg[NB] = E;
}

// packed edge: (dst&511)<<17 | src   (requires src < 2^17; N=100000 ok)
__global__ void scatter1_kernel(const int* __restrict__ src, const int* __restrict__ dst,
                                const int* __restrict__ cnt, const int* __restrict__ groupBeg,
                                int* __restrict__ pe, int E, int nChunks) {
    __shared__ int offs[NB];
    int t = threadIdx.x, b = blockIdx.x;
    offs[t] = cnt[(size_t)t * nChunks + b] + groupBeg[t];
    __syncthreads();
    int base = b * CH;
#pragma unroll
    for (int j = 0; j < EPT; ++j) {
        int e = base + j * BLK + t;
        if (e < E) {
            int d = dst[e];
            int p = atomicAdd(&offs[d >> GSH], 1);
            pe[p] = ((d & (GSZ - 1)) << 17) | src[e];
        }
    }
}

// ---------------- pass 2: one block per 512-node group ----------------
// builds row_ptr/col, dinv, AND the prescaled bf16 layer-1 input Xa[N,8].

__global__ void group_csr_kernel(const int* __restrict__ pe, const int* __restrict__ groupBeg,
                                 int* __restrict__ col, int* __restrict__ row_ptr,
                                 float* __restrict__ dinv, const float* __restrict__ x,
                                 uint4* __restrict__ xa, int N, int E) {
    __shared__ int hist[GSZ];
    __shared__ int scn[GSZ];
    __shared__ int part[256];
    int g = blockIdx.x, t = threadIdx.x;
    hist[t] = 0; hist[t + 256] = 0;
    __syncthreads();
    int lo = groupBeg[g], hi = groupBeg[g + 1];
    for (int e = lo + t; e < hi; e += BLK)
        atomicAdd(&hist[pe[e] >> 17], 1);
    __syncthreads();
    int a0 = hist[2 * t], a1 = hist[2 * t + 1];
    int s2 = a0 + a1;
    part[t] = s2;
    __syncthreads();
    for (int off = 1; off < 256; off <<= 1) {
        int xx = (t >= off) ? part[t - off] : 0;
        __syncthreads();
        if (t >= off) part[t] += xx;
        __syncthreads();
    }
    int excl = part[t] - s2;
    scn[2 * t] = excl;
    scn[2 * t + 1] = excl + a0;
    __syncthreads();
#pragma unroll
    for (int i = t; i < GSZ; i += BLK) {
        int d = (g << GSH) + i;
        if (d < N) {
            row_ptr[d] = lo + scn[i];
            float di = rsqrtf((float)hist[i] + 1.0f);   // +1 self-loop
            dinv[d] = di;
            const float* r = x + (size_t)d * 5;          // prescale fused
            uint4 u;
            u.x = pack2(r[0] * di, r[1] * di);
            u.y = pack2(r[2] * di, r[3] * di);
            u.z = pack2(r[4] * di, 0.f);
            u.w = 0u;
            xa[d] = u;
        }
    }
    if (g == 0 && t == 0) row_ptr[N] = E;
    __syncthreads();
    hist[t] = scn[t]; hist[t + 256] = scn[t + 256];   // reuse as cursors
    __syncthreads();
    for (int e = lo + t; e < hi; e += BLK) {
        int v = pe[e];
        int p = atomicAdd(&hist[v >> 17], 1);
        col[lo + p] = v & 0x1FFFF;   // within this block's window only
    }
}

// ---------------- fused gather + matmul per layer ----------------
// Phase A: stage col slab + W + b in LDS; gather bf16 neighbor rows (fp32 acc)
// into padded LDS rows. Phase B: matmul from LDS, fused epilogue
// relu(dinv*acc+b)[*dinv], bf16 output.

template <int F, int FIN, int FOUT, int CAP, bool PRESCALE_OUT>
__global__ void fused_layer_kernel(const int* __restrict__ row_ptr, const int* __restrict__ col,
                                   const uint4* __restrict__ xb, const float* __restrict__ W,
                                   const float* __restrict__ bias, const float* __restrict__ dinv,
                                   uint2* __restrict__ outb, int N) {
    constexpr int TPN = F / 8;          // threads per node (gather)
    constexpr int NPB = 256 / TPN;      // nodes per block
    constexpr int RQ  = F / 8;          // uint4 per bf16 input row
    constexpr int QO  = FOUT / 4;       // float4 outputs per row
    constexpr int STR = F + 1;          // padded LDS row stride
    __shared__ int lcol[CAP];
    __shared__ int lrp[NPB + 1];
    __shared__ __align__(16) float gl[NPB * STR];
    __shared__ __align__(16) float wl[FIN * FOUT];
    __shared__ __align__(16) float bl[FOUT];
    int t = threadIdx.x;
    int n0 = blockIdx.x * NPB;
    for (int i = t; i <= NPB; i += 256) lrp[i] = row_ptr[min(n0 + i, N)];
    for (int i = t; i < FIN * FOUT / 4; i += 256)
        ((float4*)wl)[i] = ((const float4*)W)[i];
    for (int i = t; i < FOUT; i += 256) bl[i] = bias[i];
    __syncthreads();
    int base = lrp[0];
    int total = lrp[NPB] - base;
    int stage = total < CAP ? total : CAP;
    for (int i = t; i < stage; i += 256) lcol[i] = col[base + i];
    __syncthreads();
    {   // phase A: gather
        int ln = t / TPN, q = t % TPN;
        int n = n0 + ln;
        if (n < N) {
            float acc[8];
            uint4 u = xb[(size_t)n * RQ + q];   // self term
            acc[0] = bfu_lo(u.x); acc[1] = bfu_hi(u.x);
            acc[2] = bfu_lo(u.y); acc[3] = bfu_hi(u.y);
            acc[4] = bfu_lo(u.z); acc[5] = bfu_hi(u.z);
            acc[6] = bfu_lo(u.w); acc[7] = bfu_hi(u.w);
            int beg = lrp[ln] - base, end = lrp[ln + 1] - base;
            int stop = end < stage ? end : stage;
            int e = beg;
            for (; e + 3 < stop; e += 4) {   // 4 outstanding loads
                int s0 = lcol[e], s1 = lcol[e + 1], s2 = lcol[e + 2], s3 = lcol[e + 3];
                uint4 u0 = xb[(size_t)s0 * RQ + q];
                uint4 u1 = xb[(size_t)s1 * RQ + q];
                uint4 u2 = xb[(size_t)s2 * RQ + q];
                uint4 u3 = xb[(size_t)s3 * RQ + q];
                acc[0] += bfu_lo(u0.x) + bfu_lo(u1.x) + bfu_lo(u2.x) + bfu_lo(u3.x);
                acc[1] += bfu_hi(u0.x) + bfu_hi(u1.x) + bfu_hi(u2.x) + bfu_hi(u3.x);
                acc[2] += bfu_lo(u0.y) + bfu_lo(u1.y) + bfu_lo(u2.y) + bfu_lo(u3.y);
                acc[3] += bfu_hi(u0.y) + bfu_hi(u1.y) + bfu_hi(u2.y) + bfu_hi(u3.y);
                acc[4] += bfu_lo(u0.z) + bfu_lo(u1.z) + bfu_lo(u2.z) + bfu_lo(u3.z);
                acc[5] += bfu_hi(u0.z) + bfu_hi(u1.z) + bfu_hi(u2.z) + bfu_hi(u3.z);
                acc[6] += bfu_lo(u0.w) + bfu_lo(u1.w) + bfu_lo(u2.w) + bfu_lo(u3.w);
                acc[7] += bfu_hi(u0.w) + bfu_hi(u1.w) + bfu_hi(u2.w) + bfu_hi(u3.w);
            }
            for (; e < end; ++e) {
                int s = (e < stage) ? lcol[e] : col[base + e];   // cold fallback
                uint4 uu = xb[(size_t)s * RQ + q];
                acc[0] += bfu_lo(uu.x); acc[1] += bfu_hi(uu.x);
                acc[2] += bfu_lo(uu.y); acc[3] += bfu_hi(uu.y);
                acc[4] += bfu_lo(uu.z); acc[5] += bfu_hi(uu.z);
                acc[6] += bfu_lo(uu.w); acc[7] += bfu_hi(uu.w);
            }
            float* gr = gl + ln * STR + q * 8;
#pragma unroll
            for (int j = 0; j < 8; ++j) gr[j] = acc[j];
        }
    }
    __syncthreads();
    // phase B: matmul from LDS
    for (int task = t; task < NPB * QO; task += 256) {
        int ln2 = task / QO, qq = task % QO;
        int n2 = n0 + ln2;
        if (n2 >= N) continue;
        float di = dinv[n2];
        const float* row = gl + ln2 * STR;
        float4 acc = make_float4(0.f, 0.f, 0.f, 0.f);
#pragma unroll
        for (int k = 0; k < FIN; ++k) {
            float rk = row[k];
            float4 wk = *(const float4*)(wl + k * FOUT + 4 * qq);
            acc.x = fmaf(rk, wk.x, acc.x);
            acc.y = fmaf(rk, wk.y, acc.y);
            acc.z = fmaf(rk, wk.z, acc.z);
            acc.w = fmaf(rk, wk.w, acc.w);
        }
        float4 bq = *(const float4*)(bl + 4 * qq);
        float4 v;
        v.x = fmaxf(di * acc.x + bq.x, 0.f);
        v.y = fmaxf(di * acc.y + bq.y, 0.f);
        v.z = fmaxf(di * acc.z + bq.z, 0.f);
        v.w = fmaxf(di * acc.w + bq.w, 0.f);
        if (PRESCALE_OUT) { v.x *= di; v.y *= di; v.z *= di; v.w *= di; }
        uint2 o;
        o.x = pack2(v.x, v.y);
        o.y = pack2(v.z, v.w);
        outb[(size_t)n2 * QO + qq] = o;
    }
}

// ---------------- pool + head (atomic-free, bf16 input) ----------------

__global__ void bounds_kernel(const int* __restrict__ batch, int* __restrict__ start,
                              int N, int G) {
    int g = blockIdx.x * blockDim.x + threadIdx.x;
    if (g > G) return;
    if (g == G) { start[G] = N; return; }
    int lo = 0, hi = N;
    while (lo < hi) {
        int mid = (lo + hi) >> 1;
        if (batch[mid] < g) lo = mid + 1; else hi = mid;
    }
    start[g] = lo;
}

// h = bf16 [N,64] as uint [N,32]
__global__ void pool_head_kernel(const unsigned int* __restrict__ h, const int* __restrict__ start,
                                 const float* __restrict__ Wfc, const float* __restrict__ bfc,
                                 float* __restrict__ out) {
    __shared__ float part[8][64];
    int g = blockIdx.x;
    int t = threadIdx.x;          // 256
    int u = t & 31, w = t >> 5;
    int s = start[g], e = start[g + 1];
    float a0 = 0.f, a1 = 0.f;
    for (int n = s + w; n < e; n += 8) {
        unsigned int word = h[(size_t)n * 32 + u];
        a0 += bfu_lo(word);
        a1 += bfu_hi(word);
    }
    part[w][2 * u]     = a0;
    part[w][2 * u + 1] = a1;
    __syncthreads();
    if (t < 64) {
        float p = 0.f;
#pragma unroll
        for (int w2 = 0; w2 < 8; ++w2) p += part[w2][t];
        p /= fmaxf((float)(e - s), 1.0f);
        float l0 = p * Wfc[t * 2 + 0];
        float l1 = p * Wfc[t * 2 + 1];
#pragma unroll
        for (int off = 32; off; off >>= 1) {
            l0 += __shfl_down(l0, off);
            l1 += __shfl_down(l1, off);
        }
        if (t == 0) {
            l0 += bfc[0]; l1 += bfc[1];
            float m   = fmaxf(l0, l1);
            float lse = m + logf(expf(l0 - m) + expf(l1 - m));
            out[g * 2 + 0] = l0 - lse;
            out[g * 2 + 1] = l1 - lse;
        }
    }
}

// ---------------- driver ----------------

extern "C" void kernel_launch(void* const* d_in, const int* in_sizes, int n_in,
                              void* d_out, int out_size, void* d_ws, size_t ws_size,
                              hipStream_t stream) {
    const float* x     = (const float*)d_in[0];
    const int*   src   = (const int*)d_in[1];
    const int*   dst   = (const int*)d_in[2];
    const int*   batch = (const int*)d_in[3];
    const float* W1    = (const float*)d_in[4];
    const float* b1    = (const float*)d_in[5];
    const float* W2    = (const float*)d_in[6];
    const float* b2    = (const float*)d_in[7];
    const float* W3    = (const float*)d_in[8];
    const float* b3    = (const float*)d_in[9];
    const float* Wfc   = (const float*)d_in[10];
    const float* bfc   = (const float*)d_in[11];
    float* out = (float*)d_out;

    const int N = in_sizes[0] / 5;   // 100000  (must stay < 2^17 for packed pe)
    const int E = in_sizes[1];       // 1600000
    const int G = out_size / 2;      // 1024

    const int nChunks = (E + CH - 1) / CH;           // 391
    const int M       = NB * nChunks;                // ~100K
    const int Mpad    = (M + 3) & ~3;
    const int nGroups = (N + GSZ - 1) / GSZ;         // 196

    // workspace layout (4B units; all region sizes multiples of 4; N%4==0)
    int* row_ptr  = (int*)d_ws;                   // N+4 (uses N+1)
    int* col      = row_ptr + N + 4;              // E
    int* cnt      = col + E;                      // Mpad
    int* groupBeg = cnt + Mpad;                   // 260 (uses NB+1)
    int* bucketTot= groupBeg + 260;               // 256
    int* start    = bucketTot + 256;              // G+8 (uses G+1)
    float* dinv   = (float*)(start + G + 8);      // N
    int*   Xa     = (int*)(dinv + N);             // N*16 ints: Xs1[N,8] then Xs3[N,32] bf16
    int*   Xb     = Xa + (size_t)N * 16;          // N*8  ints: Xs2[N,16] bf16
    int*   H3b    = Xb + (size_t)N * 8;           // N*32 ints: out3[N,64] bf16
    int*   pe     = H3b;                          // E ints (aliases H3b; dead before layer 3)
    // total ~ 30 MB

    auto blocks = [](long n) { return (int)((n + BLK - 1) / BLK); };

    // ---- CSR build: exact counting sort; parallel separable scan ----
    hist1_kernel<<<nChunks, 256, 0, stream>>>(dst, cnt, E, nChunks);
    seg_scan_kernel<<<NB, 256, 0, stream>>>(cnt, bucketTot, nChunks);
    bucket_scan_kernel<<<1, 256, 0, stream>>>(bucketTot, groupBeg, E);
    scatter1_kernel<<<nChunks, 256, 0, stream>>>(src, dst, cnt, groupBeg, pe, E, nChunks);
    group_csr_kernel<<<nGroups, 256, 0, stream>>>(pe, groupBeg, col, row_ptr, dinv,
                                                  x, (uint4*)Xa, N, E);   // + fused prescale

    // ---- pool boundaries ----
    bounds_kernel<<<blocks(G + 1), BLK, 0, stream>>>(batch, start, N, G);

    // ---- layer 1: Xa[N,8] -> Xb[N,16]   (F=8: 256 nodes/block) ----
    fused_layer_kernel<8, 5, 16, 6144, true><<<(N + 255) / 256, 256, 0, stream>>>(
        row_ptr, col, (const uint4*)Xa, W1, b1, dinv, (uint2*)Xb, N);

    // ---- layer 2: Xb[N,16] -> Xa[N,32]  (F=16: 128 nodes/block) ----
    fused_layer_kernel<16, 16, 32, 4096, true><<<(N + 127) / 128, 256, 0, stream>>>(
        row_ptr, col, (const uint4*)Xb, W2, b2, dinv, (uint2*)Xa, N);

    // ---- layer 3: Xa[N,32] -> H3b[N,64] (F=32: 64 nodes/block) ----
    fused_layer_kernel<32, 32, 64, 2048, false><<<(N + 63) / 64, 256, 0, stream>>>(
        row_ptr, col, (const uint4*)Xa, W3, b3, dinv, (uint2*)H3b, N);

    // ---- mean pool + head (no atomics, bf16 input) ----
    pool_head_kernel<<<G, 256, 0, stream>>>((const unsigned int*)H3b, start, Wfc, bfc, out);
}